// Round 5
// baseline (122.964 us; speedup 1.0000x reference)
//
#include <hip/hip_runtime.h>
#include <math.h>

#define B_ 4
#define N_ 4096
#define K_ 16
#define WAVES 8
#define QPB (WAVES*2)            // 2 queries per wave
#define BPB (N_/QPB)             // 256 blocks per (job,b)
#define NBUCK 512
#define INF __builtin_huge_valf()
#define SLACK 1e-4f              // covers f32 rounding mismatch bound-vs-ballot

__device__ __forceinline__ float dpp_shr1_f(float x) {
    return __int_as_float(__builtin_amdgcn_update_dpp(
        __float_as_int(x), __float_as_int(x), 0x111, 0xF, 0xF, false));
}
__device__ __forceinline__ int dpp_shr1_i(int x) {
    return __builtin_amdgcn_update_dpp(x, x, 0x111, 0xF, 0xF, false);
}
__device__ __forceinline__ float readlane_f(float x, int l) {
    return __int_as_float(__builtin_amdgcn_readlane(__float_as_int(x), l));
}
#if __has_builtin(__builtin_amdgcn_inverse_ballot_w64)
#define LANEBIT(m, lane) __builtin_amdgcn_inverse_ballot_w64(m)
#else
#define LANEBIT(m, lane) ((((m) >> (lane)) & 1ull) != 0)
#endif

// pop loop: merge balloted candidates of tile (base tbase) into sorted 16-list
#define POPS(m, dd, sdv, siv, tauv, tbase)                                 \
    if (m) {                                                               \
        do {                                                               \
            int src = __builtin_ctzll(m); m &= m - 1;                      \
            float v = readlane_f(dd, src);                                 \
            int  vi = (tbase) + src;                                       \
            bool gt = (sdv > v);                                           \
            unsigned long long mg = __ballot(gt);                          \
            float usd = dpp_shr1_f(sdv); int usi = dpp_shr1_i(siv);        \
            bool pg = LANEBIT(mg << 1, lane);                              \
            sdv = gt ? (pg ? usd : v ) : sdv;                              \
            siv = gt ? (pg ? usi : vi) : siv;                              \
        } while (m);                                                       \
        tauv = readlane_f(sdv, 15);                                        \
    }

// ------------- counting-sort each (set,b) cloud by z into float4(x,y,z,org) -
__global__ __launch_bounds__(512) void sortz_kernel(
    const float* __restrict__ ori, const float* __restrict__ adv,
    float4* __restrict__ gs)
{
    __shared__ int hist[NBUCK];
    __shared__ int base[NBUCK];
    __shared__ unsigned short sbuck[N_];
    const int tid = threadIdx.x;
    const int set = blockIdx.x >> 2;
    const int b   = blockIdx.x & 3;
    const float* src = (set ? adv : ori) + (size_t)b * (N_*3);
    float4* dst = gs + (size_t)blockIdx.x * N_;

    hist[tid] = 0;
    __syncthreads();
    #pragma unroll
    for (int k = 0; k < N_/512; ++k) {
        int j = k*512 + tid;
        float z = src[3*j+2];
        int bu = (int)((z + 4.25f) * (NBUCK/8.5f));
        bu = bu < 0 ? 0 : (bu > NBUCK-1 ? NBUCK-1 : bu);
        sbuck[j] = (unsigned short)bu;
        atomicAdd(&hist[bu], 1);
    }
    __syncthreads();
    int v = hist[tid];
    for (int s = 1; s < NBUCK; s <<= 1) {       // Hillis-Steele inclusive scan
        base[tid] = v; __syncthreads();
        if (tid >= s) v += base[tid - s];
        __syncthreads();
    }
    base[tid] = v - hist[tid];                  // exclusive prefix
    hist[tid] = 0;                              // reuse as cursor
    __syncthreads();
    #pragma unroll
    for (int k = 0; k < N_/512; ++k) {
        int j = k*512 + tid;
        int bu = sbuck[j];
        int pos = base[bu] + atomicAdd(&hist[bu], 1);
        dst[pos] = make_float4(src[3*j+0], src[3*j+1], src[3*j+2],
                               __int_as_float(j));
    }
}

// staging + per-tile z stats, shared by both scan kernels
#define STAGE_AND_STATS(gsrc)                                              \
    _Pragma("unroll")                                                      \
    for (int k = 0; k < N_/512; ++k) {                                     \
        int j = k*512 + tid;                                               \
        float4 f = (gsrc)[j];                                              \
        sxy[j] = make_float2(f.x, f.y);                                    \
        szs[j] = f.z;                                                      \
    }                                                                      \
    __syncthreads();                                                       \
    _Pragma("unroll")                                                      \
    for (int i = 0; i < 8; ++i) {                                          \
        int t = w*8 + i;                                                   \
        float zv = szs[t*64 + lane];                                       \
        float mn = zv, mx = zv;                                            \
        _Pragma("unroll")                                                  \
        for (int s = 1; s < 64; s <<= 1) {                                 \
            mn = fminf(mn, __shfl_xor(mn, s));                             \
            mx = fmaxf(mx, __shfl_xor(mx, s));                             \
        }                                                                  \
        if (lane == 0) { tmn[t] = mn; tmx[t] = mx; }                       \
    }                                                                      \
    __syncthreads();                                                       \
    if (w == 0) {                                                          \
        float a = tmn[lane], c = tmx[lane];                                \
        _Pragma("unroll")                                                  \
        for (int s = 1; s < 64; s <<= 1) {                                 \
            float u = __shfl_down(a, s); if (lane + s < 64) a = fminf(a,u);\
            float u2 = __shfl_up(c, s);  if (lane >= s)     c = fmaxf(c,u2);\
        }                                                                  \
        sufmn[lane] = a; prfmx[lane] = c;                                  \
    }                                                                      \
    __syncthreads();

// ---------------- argmin(adv -> ori): candidates sorted ori, queries sorted adv
__global__ __launch_bounds__(512, 6) void curv_argmin_kernel(
    const float4* __restrict__ gs, int* __restrict__ nnidx)
{
    __shared__ float2 sxy[N_];
    __shared__ float  szs[N_];
    __shared__ float  tmn[64], tmx[64], sufmn[64], prfmx[64];
    const int tid = threadIdx.x, lane = tid & 63, w = tid >> 6;
    const int b  = blockIdx.x >> 8;
    const int qb = (blockIdx.x & 255) * QPB;
    const float4* go = gs + (size_t)b * N_;
    const float4* ga = gs + (size_t)(4 + b) * N_;

    STAGE_AND_STATS(go)

    const int sq0 = qb + w*2, sq1 = sq0 + 1;
    float4 f0 = ga[sq0], f1 = ga[sq1];
    const int n0 = __float_as_int(f0.w), n1 = __float_as_int(f1.w);
    const float m2x0 = -2.f*f0.x, m2y0 = -2.f*f0.y, m2z0 = -2.f*f0.z;
    const float m2x1 = -2.f*f1.x, m2y1 = -2.f*f1.y, m2z1 = -2.f*f1.z;
    const float qq0 = fmaf(f0.z,f0.z, fmaf(f0.y,f0.y, f0.x*f0.x));
    const float qq1 = fmaf(f1.z,f1.z, fmaf(f1.y,f1.y, f1.x*f1.x));
    const float q0z = f0.z, q1z = f1.z;

    // start tile: binary search in monotone sufmn
    int T0;
    { int l = 0, h = 64;
      while (h - l > 1) { int m = (l+h)>>1; T0 = m; if (sufmn[m] <= q0z) l = m; else h = m; }
      T0 = l; }

    float dm0 = INF, dm1 = INF; int jm0 = 0, jm1 = 0;  // per-lane best
    float bm0 = INF, bm1 = INF;                        // wave best (prune bound)
#define APROC(t)                                                           \
    {   int j = (t)*64 + lane;                                             \
        float2 p = sxy[j]; float pz = szs[j];                              \
        float pp = fmaf(pz,pz, fmaf(p.y,p.y, p.x*p.x));                    \
        float r0 = fmaf(pz,m2z0, fmaf(p.y,m2y0, fmaf(p.x,m2x0, pp)));      \
        float r1 = fmaf(pz,m2z1, fmaf(p.y,m2y1, fmaf(p.x,m2x1, pp)));      \
        if (r0 < dm0) { dm0 = r0; jm0 = j; }                               \
        if (r1 < dm1) { dm1 = r1; jm1 = j; }                               \
        float g0 = dm0, g1 = dm1;                                          \
        _Pragma("unroll")                                                  \
        for (int s = 1; s < 64; s <<= 1) {                                 \
            g0 = fminf(g0, __shfl_xor(g0, s));                             \
            g1 = fminf(g1, __shfl_xor(g1, s));                             \
        }                                                                  \
        bm0 = g0; bm1 = g1; }

    APROC(T0)
    int tup = T0 + 1, tdn = T0 - 1;
    for (;;) {
        bool go_up = false, go_dn = false;
        if (tup < 64) {
            float m = sufmn[tup];
            float a0 = m - q0z, a1 = m - q1z;
            go_up = !((a0 > 0.f) && (fmaf(a0,a0,-qq0) >= bm0 + SLACK)) ||
                    !((a1 > 0.f) && (fmaf(a1,a1,-qq1) >= bm1 + SLACK));
        }
        if (tdn >= 0) {
            float m = prfmx[tdn];
            float a0 = q0z - m, a1 = q1z - m;
            go_dn = !((a0 > 0.f) && (fmaf(a0,a0,-qq0) >= bm0 + SLACK)) ||
                    !((a1 > 0.f) && (fmaf(a1,a1,-qq1) >= bm1 + SLACK));
        }
        if (go_up) { APROC(tup) ++tup; }
        if (go_dn) { APROC(tdn) --tdn; }
        if (!go_up && !go_dn) break;
    }
#undef APROC
    #pragma unroll
    for (int s = 1; s < 64; s <<= 1) {          // final (value, idx) argmin
        float o0 = __shfl_xor(dm0, s); int a0 = __shfl_xor(jm0, s);
        float o1 = __shfl_xor(dm1, s); int a1 = __shfl_xor(jm1, s);
        if (o0 < dm0 || (o0 == dm0 && a0 < jm0)) { dm0 = o0; jm0 = a0; }
        if (o1 < dm1 || (o1 == dm1 && a1 < jm1)) { dm1 = o1; jm1 = a1; }
    }
    if (lane == 0) {
        nnidx[b*N_ + n0] = __float_as_int(go[jm0].w);
        nnidx[b*N_ + n1] = __float_as_int(go[jm1].w);
    }
}

// ---------------- kappa for both sets (queries in sorted order) --------------
__global__ __launch_bounds__(512, 6) void curv_kappa_kernel(
    const float4* __restrict__ gs, const float* __restrict__ nrm,
    const int* __restrict__ nnidx, double* __restrict__ acc)
{
    __shared__ float2 sxy[N_];
    __shared__ float  szs[N_];
    __shared__ float  tmn[64], tmx[64], sufmn[64], prfmx[64];
    __shared__ double rs[WAVES], rss[WAVES];
    const int tid = threadIdx.x, lane = tid & 63, w = tid >> 6;
    const int blk = blockIdx.x;
    const int job = blk >> 10;
    const int b   = (blk >> 8) & 3;
    const int qb  = (blk & 255) * QPB;
    const float4* g = gs + (size_t)(job*4 + b) * N_;
    const float* nb = nrm + (size_t)b * (N_*3);

    STAGE_AND_STATS(g)

    const int sq0 = qb + w*2, sq1 = sq0 + 1;    // same tile (sq0 even)
    float4 f0 = g[sq0], f1 = g[sq1];
    const int n0 = __float_as_int(f0.w), n1 = __float_as_int(f1.w);
    const float q0x=f0.x, q0y=f0.y, q0z=f0.z;
    const float q1x=f1.x, q1y=f1.y, q1z=f1.z;
    const float m2x0 = -2.f*q0x, m2y0 = -2.f*q0y, m2z0 = -2.f*q0z;
    const float m2x1 = -2.f*q1x, m2y1 = -2.f*q1y, m2z1 = -2.f*q1z;
    const float qq0 = fmaf(q0z,q0z, fmaf(q0y,q0y, q0x*q0x));
    const float qq1 = fmaf(q1z,q1z, fmaf(q1y,q1y, q1x*q1x));

    int nn0 = n0, nn1 = n1;
    if (job) { nn0 = nnidx[b*N_+n0]; nn1 = nnidx[b*N_+n1]; }
    const float nx0 = nb[3*nn0+0], ny0 = nb[3*nn0+1], nz0 = nb[3*nn0+2];
    const float nx1 = nb[3*nn1+0], ny1 = nb[3*nn1+1], nz1 = nb[3*nn1+2];

    // ---- start tile T0 (contains both queries): bitonic sort 64 ----
    const int T0 = sq0 >> 6;
    float r0, r1; int i0 = T0*64 + lane, i1 = i0;
    {
        float2 p = sxy[i0]; float pz = szs[i0];
        float pp = fmaf(pz,pz, fmaf(p.y,p.y, p.x*p.x));
        r0 = fmaf(pz,m2z0, fmaf(p.y,m2y0, fmaf(p.x,m2x0, pp)));
        r1 = fmaf(pz,m2z1, fmaf(p.y,m2y1, fmaf(p.x,m2x1, pp)));
        if (lane == (sq0 & 63)) r0 = INF;       // exclude self
        if (lane == (sq1 & 63)) r1 = INF;
    }
    #pragma unroll
    for (int k = 2; k <= 64; k <<= 1) {
        #pragma unroll
        for (int j = k >> 1; j > 0; j >>= 1) {
            bool sel = ((lane & k) == 0) == ((lane & j) == 0);
            float o0 = __shfl_xor(r0, j); int a0 = __shfl_xor(i0, j);
            float o1 = __shfl_xor(r1, j); int a1 = __shfl_xor(i1, j);
            if ((o0 < r0) == sel) { r0 = o0; i0 = a0; }
            if ((o1 < r1) == sel) { r1 = o1; i1 = a1; }
        }
    }
    float sd0 = r0, sd1 = r1; int si0 = i0, si1 = i1;   // lanes 0..15 sorted
    float tau0 = readlane_f(sd0, 15), tau1 = readlane_f(sd1, 15);

#define KPROC(t)                                                           \
    {   int tb = (t)*64; int j = tb + lane;                                \
        float2 p = sxy[j]; float pz = szs[j];                              \
        float pp = fmaf(pz,pz, fmaf(p.y,p.y, p.x*p.x));                    \
        float d0 = fmaf(pz,m2z0, fmaf(p.y,m2y0, fmaf(p.x,m2x0, pp)));      \
        float d1 = fmaf(pz,m2z1, fmaf(p.y,m2y1, fmaf(p.x,m2x1, pp)));      \
        unsigned long long m0 = __ballot(d0 < tau0);                       \
        POPS(m0, d0, sd0, si0, tau0, tb)                                   \
        unsigned long long m1 = __ballot(d1 < tau1);                       \
        POPS(m1, d1, sd1, si1, tau1, tb) }

    int tup = T0 + 1, tdn = T0 - 1;
    for (;;) {
        bool go_up = false, go_dn = false;
        if (tup < 64) {
            float m = sufmn[tup];
            float a0 = m - q0z, a1 = m - q1z;
            go_up = !((a0 > 0.f) && (fmaf(a0,a0,-qq0) >= tau0 + SLACK)) ||
                    !((a1 > 0.f) && (fmaf(a1,a1,-qq1) >= tau1 + SLACK));
        }
        if (tdn >= 0) {
            float m = prfmx[tdn];
            float a0 = q0z - m, a1 = q1z - m;
            go_dn = !((a0 > 0.f) && (fmaf(a0,a0,-qq0) >= tau0 + SLACK)) ||
                    !((a1 > 0.f) && (fmaf(a1,a1,-qq1) >= tau1 + SLACK));
        }
        if (go_up) { KPROC(tup) ++tup; }
        if (go_dn) { KPROC(tdn) --tdn; }
        if (!go_up && !go_dn) break;
    }
#undef KPROC

    // ---- kappa = mean_k |dot(normalize(nn - q), normal)| ----
    float tl0 = 0.0f, tl1 = 0.0f;
    if (lane < K_) {
        {
            float2 p = sxy[si0]; float pz = szs[si0];
            float vx = p.x - q0x, vy = p.y - q0y, vz = pz - q0z;
            float L  = sqrtf(vx*vx + vy*vy + vz*vz) + 1e-12f;
            tl0 = fabsf(vx*nx0 + vy*ny0 + vz*nz0) / L;
        }
        {
            float2 p = sxy[si1]; float pz = szs[si1];
            float vx = p.x - q1x, vy = p.y - q1y, vz = pz - q1z;
            float L  = sqrtf(vx*vx + vy*vy + vz*vz) + 1e-12f;
            tl1 = fabsf(vx*nx1 + vy*ny1 + vz*nz1) / L;
        }
    }
    tl0 += __shfl_xor(tl0, 1); tl0 += __shfl_xor(tl0, 2);
    tl0 += __shfl_xor(tl0, 4); tl0 += __shfl_xor(tl0, 8);
    tl1 += __shfl_xor(tl1, 1); tl1 += __shfl_xor(tl1, 2);
    tl1 += __shfl_xor(tl1, 4); tl1 += __shfl_xor(tl1, 8);

    if (lane == 0) {
        double k0 = (double)tl0 * (1.0/16.0);
        double k1 = (double)tl1 * (1.0/16.0);
        rs[w]  = k0 + k1;
        rss[w] = k0*k0 + k1*k1;
    }
    __syncthreads();
    if (tid == 0) {
        double s = 0.0, ss = 0.0;
        #pragma unroll
        for (int i = 0; i < WAVES; ++i) { s += rs[i]; ss += rss[i]; }
        int row = job*4 + b;
        atomicAdd(&acc[row*2+0], s);
        atomicAdd(&acc[row*2+1], ss);
    }
}

__global__ void curv_finalize_kernel(const double* __restrict__ acc,
                                     float* __restrict__ out)
{
    if (threadIdx.x == 0 && blockIdx.x == 0) {
        double st[8];
        #pragma unroll
        for (int r = 0; r < 8; ++r) {
            double s   = acc[2*r+0];
            double ss  = acc[2*r+1];
            double var = (ss - s*s / (double)N_) / (double)(N_ - 1);
            st[r] = var > 0.0 ? sqrt(var) : 0.0;
        }
        double o = 0.0;
        #pragma unroll
        for (int bb = 0; bb < 4; ++bb) o += fabs(st[4+bb] - st[bb]);
        out[0] = (float)(o * 0.25);
    }
}

extern "C" void kernel_launch(void* const* d_in, const int* in_sizes, int n_in,
                              void* d_out, int out_size, void* d_ws, size_t ws_size,
                              hipStream_t stream)
{
    const float* ori = (const float*)d_in[0];
    const float* adv = (const float*)d_in[1];
    const float* nrm = (const float*)d_in[2];
    double* acc   = (double*)d_ws;
    int*    nnidx = (int*)((char*)d_ws + 256);
    float4* gs    = (float4*)((char*)d_ws + 256 + 65536);
    float*  out   = (float*)d_out;

    hipMemsetAsync(acc, 0, 16 * sizeof(double), stream);
    sortz_kernel<<<8, 512, 0, stream>>>(ori, adv, gs);
    curv_argmin_kernel<<<dim3(B_ * BPB), 512, 0, stream>>>(gs, nnidx);
    curv_kappa_kernel<<<dim3(2 * B_ * BPB), 512, 0, stream>>>(gs, nrm, nnidx, acc);
    curv_finalize_kernel<<<1, 64, 0, stream>>>(acc, out);
}